// Round 1
// baseline (1993.780 us; speedup 1.0000x reference)
//
#include <hip/hip_runtime.h>
#include <math.h>

#define Bc 256
#define Lc 201
#define Dc 1536
#define Hc 64
#define DHc 32
#define FFc 256
#define Nc (Bc*Lc)   // 51456 = 804*64 exactly

static constexpr size_t OFF1 = (size_t)Bc*(Lc-1)*Hc;          // 3,276,800
static constexpr size_t OFF2 = 2*OFF1;                        // 6,553,600
static constexpr size_t OFF3 = 3*OFF1;                        // 9,830,400
static constexpr size_t OFFS = OFF3 + (size_t)Bc*Lc*2*Hc;     // 16,416,768

__device__ __forceinline__ float wsum(float v){
  #pragma unroll
  for(int o=32;o>0;o>>=1) v += __shfl_xor(v,o,64);
  return v;
}
__device__ __forceinline__ float wmaxr(float v){
  #pragma unroll
  for(int o=32;o>0;o>>=1) v = fmaxf(v, __shfl_xor(v,o,64));
  return v;
}
__device__ __forceinline__ float gelu_t(float x){
  float x3 = x*x*x;
  return 0.5f*x*(1.f + tanhf(0.7978845608028654f*(x + 0.044715f*x3)));
}

// dot4 accumulate: acc += a·b (4 fmas)
#define DOT4(ACC,A,B) ACC = fmaf((A).x,(B).x, fmaf((A).y,(B).y, fmaf((A).z,(B).z, fmaf((A).w,(B).w,(ACC)))))
#define TILE16(ACC) \
  DOT4(ACC[0][0],a0,b0); DOT4(ACC[0][1],a0,b1); DOT4(ACC[0][2],a0,b2); DOT4(ACC[0][3],a0,b3); \
  DOT4(ACC[1][0],a1,b0); DOT4(ACC[1][1],a1,b1); DOT4(ACC[1][2],a1,b2); DOT4(ACC[1][3],a1,b3); \
  DOT4(ACC[2][0],a2,b0); DOT4(ACC[2][1],a2,b1); DOT4(ACC[2][2],a2,b2); DOT4(ACC[2][3],a2,b3); \
  DOT4(ACC[3][0],a3,b0); DOT4(ACC[3][1],a3,b1); DOT4(ACC[3][2],a3,b2); DOT4(ACC[3][3],a3,b3)

// ---------------- one-time weight transposes (all B-operands become K-contiguous)
__global__ __launch_bounds__(256) void k_prep(
    const float* __restrict__ fcw, const float* __restrict__ wqkv,
    const float* __restrict__ wo,  const float* __restrict__ mw,
    const float* __restrict__ w1,  const float* __restrict__ w2,
    float* __restrict__ fwT, float* __restrict__ wqT, float* __restrict__ woT,
    float* __restrict__ mwT, float* __restrict__ w1T, float* __restrict__ w2T){
  int b = blockIdx.x, tid = threadIdx.x;
  if(b < 384){                                   // fcw (1536,64) -> fwT[64][1536]
    int c = b/6, k = (b - 6*(b/6))*256 + tid;
    fwT[(size_t)c*Dc + k] = fcw[(size_t)k*Hc + c];
  } else if(b < 480){                            // wqkv (2,64,192) -> wqT[2][192][64]
    int idx = (b-384)*256 + tid;
    int i = idx/12288, rem = idx - i*12288;
    int c = rem>>6, k = rem&63;
    wqT[(size_t)i*12288 + c*64 + k] = wqkv[(size_t)i*12288 + k*192 + c];
  } else if(b < 512){                            // wo (2,64,64) -> woT[2][64][64]
    int idx = (b-480)*256 + tid;
    int i = idx>>12, rem = idx&4095;
    int c = rem>>6, k = rem&63;
    woT[(size_t)i*4096 + c*64 + k] = wo[(size_t)i*4096 + k*64 + c];
  } else if(b < 528){                            // mw (64,64) -> mwT[64][64]
    int idx = (b-512)*256 + tid;
    int c = idx>>6, k = idx&63;
    mwT[(size_t)c*64 + k] = mw[(size_t)k*64 + c];
  } else if(b < 656){                            // w1 (2,64,256) -> w1T[2][256][64]
    int idx = (b-528)*256 + tid;
    int i = idx>>14, rem = idx&16383;
    int f = rem>>6, k = rem&63;
    w1T[(size_t)i*16384 + f*64 + k] = w1[(size_t)i*16384 + k*256 + f];
  } else {                                       // w2 (2,256,64) -> w2T[2][64][256]
    int idx = (b-656)*256 + tid;
    int i = idx>>14, rem = idx&16383;
    int h = rem>>8, f = rem&255;
    w2T[(size_t)i*16384 + h*256 + f] = w2[(size_t)i*16384 + f*64 + h];
  }
}

// ---------------- masked row-sum of X over L, per b; also Sb and sim zero-init
__global__ __launch_bounds__(256) void k_xsum(const float* __restrict__ X,
    const int* __restrict__ mask, float* __restrict__ xsum,
    float* __restrict__ Sb, float* __restrict__ simp){
  int b = blockIdx.x, tid = threadIdx.x;
  __shared__ float mk[Lc];
  for(int l = tid; l < Lc; l += 256) mk[l] = (float)mask[b*Lc + l];
  if(b==0 && tid==0) simp[0] = 0.f;
  __syncthreads();
  if(tid==0){ float s=0.f; for(int l=0;l<Lc;l++) s+=mk[l]; Sb[b]=s; }
  float acc[6];
  #pragma unroll
  for(int j=0;j<6;j++) acc[j]=0.f;
  const float* Xb = X + (size_t)b*Lc*Dc;
  for(int l=0;l<Lc;l++){
    if(mk[l] != 0.f){
      const float* row = Xb + (size_t)l*Dc;
      #pragma unroll
      for(int j=0;j<6;j++) acc[j] += row[j*256 + tid];
    }
  }
  #pragma unroll
  for(int j=0;j<6;j++) xsum[(size_t)b*Dc + j*256 + tid] = acc[j];
}

// ---------------- fused: Y = X@fc_w + fc_b ; out = gelu(Y@mlp_w + mlp_b)
// MODE 0: dst is (N,64) plain.  MODE 1: dst is (B,200,64), skip l==200 rows.
// fwT = fc_w^T [64][1536], mwT = mlp_w^T [64][64]
template<int MODE>
__global__ __launch_bounds__(256) void k_mlpfc(const float* __restrict__ X,
    const float* __restrict__ fwT, const float* __restrict__ fcb,
    const float* __restrict__ mwT, const float* __restrict__ mb,
    float* __restrict__ dst){
  __shared__ __align__(16) float xs[64][36];
  __shared__ __align__(16) float wts[64][36];
  __shared__ __align__(16) float yt[64][68];
  int tid = threadIdx.x;
  int n0 = blockIdx.x*64;
  int tr = tid>>4, tc = tid&15;
  float acc[4][4];
  #pragma unroll
  for(int i=0;i<4;i++){
    #pragma unroll
    for(int j=0;j<4;j++) acc[i][j]=0.f;
  }
  for(int k0=0;k0<Dc;k0+=32){
    #pragma unroll
    for(int i=0;i<8;i++){
      int idx = i*256+tid;
      int r = idx>>5, k = idx&31;
      xs[r][k]  = X[(size_t)(n0+r)*Dc + k0 + k];
      wts[r][k] = fwT[(size_t)r*Dc + k0 + k];
    }
    __syncthreads();
    #pragma unroll 4
    for(int k=0;k<32;k+=4){
      float4 a0=*(const float4*)&xs[tr   ][k];
      float4 a1=*(const float4*)&xs[tr+16][k];
      float4 a2=*(const float4*)&xs[tr+32][k];
      float4 a3=*(const float4*)&xs[tr+48][k];
      float4 b0=*(const float4*)&wts[tc   ][k];
      float4 b1=*(const float4*)&wts[tc+16][k];
      float4 b2=*(const float4*)&wts[tc+32][k];
      float4 b3=*(const float4*)&wts[tc+48][k];
      TILE16(acc);
    }
    __syncthreads();
  }
  #pragma unroll
  for(int i=0;i<4;i++){
    #pragma unroll
    for(int j=0;j<4;j++)
      yt[tr+16*i][tc+16*j] = acc[i][j] + fcb[tc+16*j];
  }
  __syncthreads();
  float acc2[4][4];
  #pragma unroll
  for(int i=0;i<4;i++){
    #pragma unroll
    for(int j=0;j<4;j++) acc2[i][j]=0.f;
  }
  #pragma unroll 4
  for(int k=0;k<64;k+=4){
    float4 a0=*(const float4*)&yt[tr   ][k];
    float4 a1=*(const float4*)&yt[tr+16][k];
    float4 a2=*(const float4*)&yt[tr+32][k];
    float4 a3=*(const float4*)&yt[tr+48][k];
    float4 b0=*(const float4*)&mwT[(size_t)(tc   )*64 + k];
    float4 b1=*(const float4*)&mwT[(size_t)(tc+16)*64 + k];
    float4 b2=*(const float4*)&mwT[(size_t)(tc+32)*64 + k];
    float4 b3=*(const float4*)&mwT[(size_t)(tc+48)*64 + k];
    TILE16(acc2);
  }
  #pragma unroll
  for(int i=0;i<4;i++){
    #pragma unroll
    for(int j=0;j<4;j++){
      int r = tr+16*i, c = tc+16*j;
      float v = gelu_t(acc2[i][j] + mb[c]);
      int n = n0 + r;
      if(MODE==0){
        dst[(size_t)n*Hc + c] = v;
      } else {
        int bb = n/Lc, l = n - bb*Lc;
        if(l < Lc-1) dst[((size_t)bb*(Lc-1) + l)*Hc + c] = v;
      }
    }
  }
}

// ---------------- collapsed GNN: gvec[b] = relu(mean_masked(X)@wg1 + bg1) @ wg2
__global__ __launch_bounds__(256) void k_gnn(const float* __restrict__ xsum,
    const float* __restrict__ Sb, const float* __restrict__ wg1,
    const float* __restrict__ bg1, const float* __restrict__ wg2,
    float* __restrict__ gvec){
  int b = blockIdx.x, tid = threadIdx.x;
  __shared__ float mx[Dc];
  __shared__ float h1s[FFc];
  float s = Sb[b];
  float inv = (s > 0.f) ? 1.f/s : 0.f;
  for(int i=tid;i<Dc;i+=256) mx[i] = xsum[(size_t)b*Dc+i]*inv;
  __syncthreads();
  float acc = 0.f;
  #pragma unroll 8
  for(int d=0;d<Dc;d++) acc += mx[d]*wg1[(size_t)d*FFc + tid];
  h1s[tid] = fmaxf(acc + bg1[tid], 0.f);
  __syncthreads();
  if(tid < Hc){
    float g = 0.f;
    #pragma unroll 8
    for(int f=0;f<FFc;f++) g += h1s[f]*wg2[f*Hc + tid];
    gvec[b*Hc + tid] = g;
  }
}

// ---------------- similarity scalar
__global__ __launch_bounds__(256) void k_sim(const float* __restrict__ emb,
    const float* __restrict__ gvec, const float* __restrict__ bg2,
    const int* __restrict__ mask, float* __restrict__ simp){
  int b = blockIdx.x, tid = threadIdx.x;
  int wave = tid >> 6, lane = tid & 63;
  float gv_on = gvec[b*Hc + lane] + bg2[lane];
  float gv_off = bg2[lane];
  float accum = 0.f;
  for(int l = wave; l < Lc; l += 4){
    float e = emb[((size_t)b*Lc + l)*Hc + lane];
    float gv = (mask[b*Lc + l] != 0) ? gv_on : gv_off;
    float num = e*gv, na2 = e*e, nb2 = gv*gv;
    #pragma unroll
    for(int o=32;o>0;o>>=1){
      num += __shfl_xor(num,o,64);
      na2 += __shfl_xor(na2,o,64);
      nb2 += __shfl_xor(nb2,o,64);
    }
    if(lane==0){
      float na = fmaxf(sqrtf(na2),1e-8f), nb = fmaxf(sqrtf(nb2),1e-8f);
      accum += num/(na*nb);
    }
  }
  __shared__ float part[4];
  if(lane==0) part[wave]=accum;
  __syncthreads();
  if(tid==0){
    float t = part[0]+part[1]+part[2]+part[3];
    atomicAdd(simp, t * (1.0f/((float)Lc*(float)Bc)));
  }
}

// ---------------- x = ln0(emb + pos_emb)
__global__ __launch_bounds__(256) void k_ln0(const float* __restrict__ emb,
    const float* __restrict__ pos, const float* __restrict__ g,
    const float* __restrict__ be, float* __restrict__ x){
  int n = blockIdx.x*4 + (threadIdx.x>>6);
  int lane = threadIdx.x & 63;
  int l = n % Lc;
  float v = emb[(size_t)n*Hc + lane] + pos[l*Hc + lane];
  float m = wsum(v)*(1.f/64.f);
  float dv = v - m;
  float var = wsum(dv*dv)*(1.f/64.f);
  float r = rsqrtf(var + 1e-5f);
  x[(size_t)n*Hc + lane] = dv*r*g[lane] + be[lane];
}

// ---------------- qkv = x @ wqkv_i + bqkv_i  (wqT = per-layer [192][64] transposed)
__global__ __launch_bounds__(256) void k_qkv(const float* __restrict__ x,
    const float* __restrict__ wqT, const float* __restrict__ bias,
    float* __restrict__ qkv){
  __shared__ __align__(16) float xs[64][68];
  __shared__ __align__(16) float wt[64][68];
  int tid=threadIdx.x, n0=blockIdx.x*64, c0=blockIdx.y*64;
  #pragma unroll
  for(int i=0;i<16;i++){
    int idx=i*256+tid; int r=idx>>6, c=idx&63;
    xs[r][c]=x[(size_t)(n0+r)*Hc+c];
    wt[r][c]=wqT[(size_t)(c0+r)*64 + c];
  }
  __syncthreads();
  int tr=tid>>4, tc=tid&15;
  float acc[4][4];
  #pragma unroll
  for(int i=0;i<4;i++){
    #pragma unroll
    for(int j=0;j<4;j++) acc[i][j]=0.f;
  }
  #pragma unroll 4
  for(int k=0;k<64;k+=4){
    float4 a0=*(const float4*)&xs[tr   ][k];
    float4 a1=*(const float4*)&xs[tr+16][k];
    float4 a2=*(const float4*)&xs[tr+32][k];
    float4 a3=*(const float4*)&xs[tr+48][k];
    float4 b0=*(const float4*)&wt[tc   ][k];
    float4 b1=*(const float4*)&wt[tc+16][k];
    float4 b2=*(const float4*)&wt[tc+32][k];
    float4 b3=*(const float4*)&wt[tc+48][k];
    TILE16(acc);
  }
  #pragma unroll
  for(int i=0;i<4;i++){
    #pragma unroll
    for(int j=0;j<4;j++){
      int r=tr+16*i, c=tc+16*j;
      qkv[(size_t)(n0+r)*(3*Hc) + c0 + c] = acc[i][j] + bias[c0+c];
    }
  }
}

// ---------------- attention for one (b, head)
// Changes: no per-iteration barriers (p_s is wave-private), PV uses all 64 lanes
// via even/odd-m split + shfl_xor(.,32), padded v_s/p_s so no inner guards.
__global__ __launch_bounds__(256) void k_attn(const float* __restrict__ qkv,
    const int* __restrict__ mask, float* __restrict__ o){
  int b = blockIdx.x, h = blockIdx.y;
  int tid = threadIdx.x;
  __shared__ float kT[DHc][Lc];
  __shared__ float v_s[204][DHc];
  __shared__ float p_s[4][204];
  __shared__ float mkf[Lc];
  size_t base = (size_t)b*Lc;
  int qoff = h*DHc, koff = Hc + h*DHc, voff = 2*Hc + h*DHc;
  for(int idx = tid; idx < Lc*DHc; idx += 256){
    int l = idx >> 5, d = idx & 31;
    const float* row = qkv + (base + l)*(3*Hc);
    kT[d][l] = row[koff + d];
    v_s[l][d] = row[voff + d];
  }
  if(tid < 96) v_s[201 + (tid>>5)][tid&31] = 0.f;     // pad rows
  if(tid < 12) p_s[tid&3][201 + (tid>>2)] = 0.f;      // pad cols
  for(int idx = tid; idx < Lc; idx += 256) mkf[idx] = (float)mask[base + idx];
  __syncthreads();
  int wave = tid >> 6, lane = tid & 63;
  const float scale = 0.17677669529663687f;  // 1/sqrt(32)
  for(int it = 0; it < 51; it++){
    int l = it*4 + wave;
    if(l < Lc){
      float qv[DHc];
      const float* qrow = qkv + (base + l)*(3*Hc) + qoff;
      #pragma unroll
      for(int d=0;d<DHc;d++) qv[d] = qrow[d];
      float e[4]; float smax = -INFINITY;
      #pragma unroll
      for(int j=0;j<4;j++){
        int m = j*64 + lane;
        float s = -INFINITY;
        if(m < Lc){
          float dot = 0.f;
          #pragma unroll
          for(int d=0; d<DHc; d++) dot += qv[d]*kT[d][m];
          s = dot*scale;
          if(!((m <= l) && (mkf[m] != 0.f))) s -= 1e9f;
        }
        e[j] = s;
        smax = fmaxf(smax, s);
      }
      smax = wmaxr(smax);
      float ssum = 0.f;
      #pragma unroll
      for(int j=0;j<4;j++){
        int m = j*64 + lane;
        float ev = (m < Lc) ? expf(e[j] - smax) : 0.f;
        e[j] = ev; ssum += ev;
      }
      ssum = wsum(ssum);
      float inv = 1.f/ssum;
      #pragma unroll
      for(int j=0;j<4;j++){
        int m = j*64 + lane;
        if(m < Lc) p_s[wave][m] = e[j]*inv;
      }
      // PV: lanes 0-31 take even m (d=lane), lanes 32-63 take odd m (d=lane&31)
      int d = lane & 31, hh = lane >> 5;
      float oacc = 0.f;
      const float* pr = &p_s[wave][0];
      #pragma unroll 4
      for(int t=0; t<102; t++){
        int m = 2*t + hh;
        oacc = fmaf(pr[m], v_s[m][d], oacc);
      }
      oacc += __shfl_xor(oacc, 32, 64);
      if(lane < DHc) o[(base + l)*Hc + h*DHc + lane] = oacc;
    }
  }
}

// ---------------- x = ln1(x + o@wo + bo)   (woT = per-layer [64][64] transposed)
__global__ __launch_bounds__(256) void k_oln(const float* __restrict__ o,
    const float* __restrict__ woT, const float* __restrict__ bo,
    const float* __restrict__ g, const float* __restrict__ be,
    float* __restrict__ x){
  __shared__ __align__(16) float os[64][68];
  __shared__ __align__(16) float wt[64][68];
  __shared__ __align__(16) float yt[64][68];
  int tid=threadIdx.x, n0=blockIdx.x*64;
  #pragma unroll
  for(int i=0;i<16;i++){
    int idx=i*256+tid; int r=idx>>6, c=idx&63;
    os[r][c]=o[(size_t)(n0+r)*Hc+c];
    wt[r][c]=woT[(size_t)r*64+c];
  }
  __syncthreads();
  int tr=tid>>4, tc=tid&15;
  float acc[4][4];
  #pragma unroll
  for(int i=0;i<4;i++){
    #pragma unroll
    for(int j=0;j<4;j++) acc[i][j]=0.f;
  }
  #pragma unroll 4
  for(int k=0;k<64;k+=4){
    float4 a0=*(const float4*)&os[tr   ][k];
    float4 a1=*(const float4*)&os[tr+16][k];
    float4 a2=*(const float4*)&os[tr+32][k];
    float4 a3=*(const float4*)&os[tr+48][k];
    float4 b0=*(const float4*)&wt[tc   ][k];
    float4 b1=*(const float4*)&wt[tc+16][k];
    float4 b2=*(const float4*)&wt[tc+32][k];
    float4 b3=*(const float4*)&wt[tc+48][k];
    TILE16(acc);
  }
  #pragma unroll
  for(int i=0;i<4;i++){
    #pragma unroll
    for(int j=0;j<4;j++){
      int r=tr+16*i, c=tc+16*j;
      yt[r][c] = acc[i][j] + bo[c] + x[(size_t)(n0+r)*Hc+c];
    }
  }
  __syncthreads();
  int wave=tid>>6, lane=tid&63;
  for(int r=wave;r<64;r+=4){
    float v = yt[r][lane];
    float m = wsum(v)*(1.f/64.f);
    float dv = v - m;
    float var = wsum(dv*dv)*(1.f/64.f);
    float rr = rsqrtf(var + 1e-5f);
    x[(size_t)(n0+r)*Hc + lane] = dv*rr*g[lane] + be[lane];
  }
}

// ---------------- x = ln2(x + gelu(x@w1+b1)@w2 + b2)
// Fused 64-row block, 4 slabs of 64 FF-cols; w1T [256][64], w2T [64][256].
__global__ __launch_bounds__(256) void k_ffn(const float* __restrict__ xin,
    const float* __restrict__ w1T, const float* __restrict__ b1,
    const float* __restrict__ w2T, const float* __restrict__ b2,
    const float* __restrict__ g, const float* __restrict__ be,
    float* __restrict__ x){
  __shared__ __align__(16) float xs[64][68];
  __shared__ __align__(16) float wa[64][68];   // w1T slab: [f_local][k]
  __shared__ __align__(16) float wb[64][68];   // w2T slab: [h][f_local]
  __shared__ __align__(16) float ts[64][68];   // gelu activations: [r][f_local]
  int tid=threadIdx.x, n0=blockIdx.x*64;
  int tr=tid>>4, tc=tid&15;
  #pragma unroll
  for(int i=0;i<16;i++){
    int idx=i*256+tid; int r=idx>>6, c=idx&63;
    xs[r][c]=xin[(size_t)(n0+r)*Hc+c];
  }
  float acc2[4][4];
  #pragma unroll
  for(int i=0;i<4;i++){
    #pragma unroll
    for(int j=0;j<4;j++) acc2[i][j]=0.f;
  }
  for(int cb=0; cb<4; cb++){
    int f0 = cb*64;
    __syncthreads();   // xs ready (cb=0); wa/wb/ts no longer read (cb>0)
    #pragma unroll
    for(int i=0;i<16;i++){
      int idx=i*256+tid; int r=idx>>6, c=idx&63;
      wa[r][c] = w1T[(size_t)(f0+r)*64 + c];
      wb[r][c] = w2T[(size_t)r*FFc + f0 + c];
    }
    __syncthreads();
    float acc1[4][4];
    #pragma unroll
    for(int i=0;i<4;i++){
      #pragma unroll
      for(int j=0;j<4;j++) acc1[i][j]=0.f;
    }
    #pragma unroll 4
    for(int k=0;k<64;k+=4){
      float4 a0=*(const float4*)&xs[tr   ][k];
      float4 a1=*(const float4*)&xs[tr+16][k];
      float4 a2=*(const float4*)&xs[tr+32][k];
      float4 a3=*(const float4*)&xs[tr+48][k];
      float4 b0=*(const float4*)&wa[tc   ][k];
      float4 b1=*(const float4*)&wa[tc+16][k];
      float4 b2=*(const float4*)&wa[tc+32][k];
      float4 b3=*(const float4*)&wa[tc+48][k];
      TILE16(acc1);
    }
    #pragma unroll
    for(int i=0;i<4;i++){
      #pragma unroll
      for(int j=0;j<4;j++)
        ts[tr+16*i][tc+16*j] = gelu_t(acc1[i][j] + b1[f0 + tc+16*j]);
    }
    __syncthreads();
    #pragma unroll 4
    for(int f=0;f<64;f+=4){
      float4 a0=*(const float4*)&ts[tr   ][f];
      float4 a1=*(const float4*)&ts[tr+16][f];
      float4 a2=*(const float4*)&ts[tr+32][f];
      float4 a3=*(const float4*)&ts[tr+48][f];
      float4 b0=*(const float4*)&wb[tc   ][f];
      float4 b1=*(const float4*)&wb[tc+16][f];
      float4 b2=*(const float4*)&wb[tc+32][f];
      float4 b3=*(const float4*)&wb[tc+48][f];
      TILE16(acc2);
    }
  }
  __syncthreads();
  #pragma unroll
  for(int i=0;i<4;i++){
    #pragma unroll
    for(int j=0;j<4;j++){
      int r=tr+16*i, c=tc+16*j;
      wa[r][c] = acc2[i][j] + b2[c] + xs[r][c];
    }
  }
  __syncthreads();
  int wave=tid>>6, lane=tid&63;
  for(int r=wave;r<64;r+=4){
    float v = wa[r][lane];
    float m = wsum(v)*(1.f/64.f);
    float dv = v - m;
    float var = wsum(dv*dv)*(1.f/64.f);
    float rr = rsqrtf(var + 1e-5f);
    x[(size_t)(n0+r)*Hc + lane] = dv*rr*g[lane] + be[lane];
  }
}

// ---------------- assemble outputs 0,1,3 and the similarity scalar
__global__ __launch_bounds__(256) void k_assemble(const float* __restrict__ emb,
    const float* __restrict__ xf, const float* __restrict__ simp,
    float* __restrict__ out){
  size_t idx = (size_t)blockIdx.x*256 + threadIdx.x;
  int h = (int)(idx & 63);
  size_t n = idx >> 6;
  int b = (int)(n / Lc);
  int l = (int)(n - (size_t)b*Lc);
  float e = emb[idx], p = xf[idx];
  out[OFF3 + n*128 + h] = e;
  out[OFF3 + n*128 + 64 + h] = p;
  if(l >= 1)   out[OFF1 + (((size_t)b*(Lc-1) + (l-1))<<6) + h] = e;
  if(l < Lc-1) out[(((size_t)b*(Lc-1) + l)<<6) + h] = p;
  if(idx == 0) out[OFFS] = simp[0];
}

extern "C" void kernel_launch(void* const* d_in, const int* in_sizes, int n_in,
                              void* d_out, int out_size, void* d_ws, size_t ws_size,
                              hipStream_t stream){
  (void)in_sizes; (void)n_in; (void)out_size; (void)ws_size;
  const float* X   = (const float*)d_in[0];
  const float* neg = (const float*)d_in[1];
  const float* fcw = (const float*)d_in[2];
  const float* fcb = (const float*)d_in[3];
  const float* mw  = (const float*)d_in[4];
  const float* mb  = (const float*)d_in[5];
  const float* pos = (const float*)d_in[6];
  const float* ln0g= (const float*)d_in[7];
  const float* ln0b= (const float*)d_in[8];
  const float* wqkv= (const float*)d_in[9];
  const float* bqkv= (const float*)d_in[10];
  const float* wo  = (const float*)d_in[11];
  const float* bo  = (const float*)d_in[12];
  const float* ln1g= (const float*)d_in[13];
  const float* ln1b= (const float*)d_in[14];
  const float* w1  = (const float*)d_in[15];
  const float* b1  = (const float*)d_in[16];
  const float* w2  = (const float*)d_in[17];
  const float* b2  = (const float*)d_in[18];
  const float* ln2g= (const float*)d_in[19];
  const float* ln2b= (const float*)d_in[20];
  const float* wg1 = (const float*)d_in[21];
  const float* bg1 = (const float*)d_in[22];
  const float* wg2 = (const float*)d_in[23];
  const float* bg2 = (const float*)d_in[24];
  const int*   msk = (const int*)d_in[25];
  float* out = (float*)d_out;

  float* ws   = (float*)d_ws;
  float* emb  = ws;                           // N*H
  float* x    = emb  + (size_t)Nc*Hc;         // N*H
  float* oatt = x    + (size_t)Nc*Hc;         // N*H
  float* qkv  = oatt + (size_t)Nc*Hc;         // N*3H
  float* xsum = qkv  + (size_t)Nc*3*Hc;       // B*D
  float* Sb   = xsum + (size_t)Bc*Dc;         // B
  float* gvec = Sb   + Bc;                    // B*H
  float* wqT  = gvec + (size_t)Bc*Hc;         // 2*192*64
  float* woT  = wqT  + 24576;                 // 2*64*64
  float* w1T  = woT  + 8192;                  // 2*256*64
  float* w2T  = w1T  + 32768;                 // 2*64*256
  float* simp = w2T  + 32768;                 // 1
  // fwT/mwT alias the qkv region: only live between k_prep and k_mlpfc,
  // both of which complete (stream-ordered) before k_qkv first writes qkv.
  float* fwT  = qkv;                          // 64*1536
  float* mwT  = qkv + (size_t)Hc*Dc;          // 64*64

  k_prep<<<784,256,0,stream>>>(fcw, wqkv, wo, mw, w1, w2,
                               fwT, wqT, woT, mwT, w1T, w2T);
  k_xsum<<<Bc,256,0,stream>>>(X, msk, xsum, Sb, simp);
  k_mlpfc<0><<<Nc/64,256,0,stream>>>(X, fwT, fcb, mwT, mb, emb);
  k_mlpfc<1><<<Nc/64,256,0,stream>>>(neg, fwT, fcb, mwT, mb, out + OFF2);
  k_gnn<<<Bc,256,0,stream>>>(xsum, Sb, wg1, bg1, wg2, gvec);
  k_sim<<<Bc,256,0,stream>>>(emb, gvec, bg2, msk, simp);
  k_ln0<<<Nc/4,256,0,stream>>>(emb, pos, ln0g, ln0b, x);
  for(int i=0;i<2;i++){
    k_qkv<<<dim3(Nc/64,3),256,0,stream>>>(x, wqT + (size_t)i*12288, bqkv + i*3*Hc, qkv);
    k_attn<<<dim3(Bc,2),256,0,stream>>>(qkv, msk, oatt);
    k_oln<<<Nc/64,256,0,stream>>>(oatt, woT + (size_t)i*4096, bo + i*Hc,
                                  ln1g + i*Hc, ln1b + i*Hc, x);
    k_ffn<<<Nc/64,256,0,stream>>>(x, w1T + (size_t)i*16384, b1 + i*FFc,
                                  w2T + (size_t)i*16384, b2 + i*Hc,
                                  ln2g + i*Hc, ln2b + i*Hc, x);
  }
  k_assemble<<<(Nc*Hc)/256,256,0,stream>>>(emb, x, simp, out);
}